// Round 11
// baseline (145.530 us; speedup 1.0000x reference)
//
#include <hip/hip_runtime.h>
#include <hip/hip_bf16.h>
#include <math.h>

#define BB 8
#define CC 64
#define HH 128
#define WW 128
#define HO 64
#define WO 128
#define OC 64
#define HW (HH * WW)
#define HOWO (HO * WO)

typedef __attribute__((ext_vector_type(8))) short short8;
typedef __attribute__((ext_vector_type(4))) float floatx4;

union BfBits { __hip_bfloat16 h; unsigned short s; };
__device__ __forceinline__ unsigned short f2bf(float f) {
    BfBits b; b.h = __float2bfloat16(f); return b.s;
}
__device__ __forceinline__ float bflo(unsigned int u) {
    return __uint_as_float(u << 16);
}
__device__ __forceinline__ float bfhi(unsigned int u) {
    return __uint_as_float(u & 0xFFFF0000u);
}

// ---------------------------------------------------------------------------
// Kernel A: all prep, 512-thread blocks.
//  blocks 0..1023   : transpose x -> xT[b][y][w][c] bf16 and paired
//                     xP[b][y][w][c] = pack(col w, col w+1). T stride 129:
//                     (c*129+w)%32=(c+w)%32 -> conflict-free both phases.
//  blocks 1024..1059: Wom[32][576] bf16 (om GEMM weights, zero-pad)
//  blocks 1060..1131: W2[k][o][c] bf16 (main MFMA A-operand layout)
// ---------------------------------------------------------------------------
__global__ __launch_bounds__(512) void prep(
    const float* __restrict__ x,
    const float* __restrict__ w_off, const float* __restrict__ w_msk,
    const float* __restrict__ w_conv,
    unsigned short* __restrict__ xT, unsigned int* __restrict__ xP,
    unsigned short* __restrict__ Wom, unsigned short* __restrict__ W2)
{
    __shared__ float T[64][129];
    int tid = threadIdx.x;
    int bx = blockIdx.x;
    if (bx < 1024) {
        int b = bx & 7, y = bx >> 3;
        int wl = tid & 127, c0 = tid >> 7;       // c0 in 0..3
#pragma unroll
        for (int i = 0; i < 16; ++i) {
            int c = 4 * i + c0;
            T[c][wl] = x[(((size_t)b * CC + c) * HH + y) * WW + wl];
        }
        __syncthreads();
        int c = tid & 63, wg = tid >> 6;         // wg in 0..7
#pragma unroll
        for (int i = 0; i < 16; ++i) {
            int wp = wg * 16 + i;
            unsigned int lo = f2bf(T[c][wp]);
            unsigned int hi = (wp < 127) ? f2bf(T[c][wp + 1]) : 0u;
            size_t e = (((size_t)b * HH + y) * WW + wp) * 64 + c;
            xT[e] = (unsigned short)lo;
            xP[e] = lo | (hi << 16);
        }
    } else if (bx < 1060) {
        int i = (bx - 1024) * 512 + tid;         // 18432 = 36*512 exact
        int ch = i / 576, kk = i % 576;
        int xs = kk >> 6, c = kk & 63;
        float v = 0.0f;
        if (ch < 18)      v = w_off[(ch * CC + c) * 9 + xs];
        else if (ch < 27) v = w_msk[((ch - 18) * CC + c) * 9 + xs];
        Wom[i] = f2bf(v);
    } else {
        int i = (bx - 1060) * 512 + tid;         // 36864 = 72*512 exact
        int k = i % 9, c = (i / 9) % CC, o = i / (CC * 9);
        W2[((size_t)k * OC + o) * CC + c] = f2bf(w_conv[i]);
    }
}

// ---------------------------------------------------------------------------
// Kernel B: FUSED om-GEMM + coeffs + sampling + main MFMA. Block=(b,h,32pos).
// Phases (4 barriers total):
//  1. stage Xs[3][34][72] from xT          (overlays S region)
//  2. om GEMM (18 MFMA) -> omr[27][33]
//  3. coeffs->metaC float4, row byte offsets->metaR uint2
//  4. ALL 9 taps sampled back-to-back (G double-buffered, SGPR-based
//     addressing via readfirstlane) into S[9][32][64]; ONE barrier;
//     36-MFMA burst; epilogue.
// LDS 47.3 KB -> 3 blocks/CU (12 waves, same as measured R10 occupancy).
// ---------------------------------------------------------------------------
__global__ __launch_bounds__(256) void fused(
    const unsigned short* __restrict__ xT, const unsigned int* __restrict__ xP,
    const unsigned short* __restrict__ Wom, const unsigned short* __restrict__ W2,
    const float* __restrict__ b_off, const float* __restrict__ b_msk,
    float* __restrict__ out)
{
    __shared__ __align__(16) char lds[47360];
    unsigned short (*S)[32][64] = (unsigned short(*)[32][64])lds;   // [9][32][64]
    typedef unsigned short XsRow[34][72];
    XsRow* Xs = (XsRow*)lds;                                        // overlay
    float (*omr)[33] = (float(*)[33])(lds + 36864);                 // [27][33]
    uint2*  metaR = (uint2*)(lds + 40432);                          // [288]
    float4* metaC = (float4*)(lds + 42736);                         // [288]

    int tid = threadIdx.x;
    int lane = tid & 63;
    int wv = __builtin_amdgcn_readfirstlane(tid >> 6);
    int bx = blockIdx.x;               // 2048 = 8b * 64h * 4wt
    int b = bx & 7;
    int rest = bx >> 3;
    int h = rest >> 2;
    int w0 = (rest & 3) * 32;
    int h2 = 2 * h - 1;
    int m16 = lane & 15, q = lane >> 4;

    // ---- phase 1: stage slab ----
    for (int u = tid; u < 816; u += 256) {       // 816 = 3*34*8
        int ky = u / 272;
        int rem = u - ky * 272;
        int col = rem >> 3, cb = rem & 7;
        int hy = h2 + ky, wc = w0 - 1 + col;
        short8 v = {0, 0, 0, 0, 0, 0, 0, 0};
        if ((unsigned)hy < (unsigned)HH && (unsigned)wc < (unsigned)WW)
            v = *(const short8*)(xT + (((size_t)b * HH + hy) * WW + wc) * 64 + cb * 8);
        *(short8*)&Xs[ky][col][cb * 8] = v;
    }
    __syncthreads();

    // ---- phase 2: om GEMM ----
    {
        int mt = wv & 1, nt = wv >> 1;
        floatx4 a = (floatx4){0.f, 0.f, 0.f, 0.f};
        const unsigned short* wa = Wom + (mt * 16 + m16) * 576 + q * 8;
#pragma unroll
        for (int t = 0; t < 18; ++t) {
            int xs = t >> 1, ky = xs / 3, kx = xs % 3;
            short8 af = *(const short8*)(wa + t * 32);
            short8 bf = *(const short8*)&Xs[ky][nt * 16 + m16 + kx][(t & 1) * 32 + q * 8];
            a = __builtin_amdgcn_mfma_f32_16x16x32_bf16(af, bf, a, 0, 0, 0);
        }
#pragma unroll
        for (int r = 0; r < 4; ++r) {
            int ch = mt * 16 + q * 4 + r;
            if (ch < 27) omr[ch][nt * 16 + m16] = a[r];
        }
    }
    __syncthreads();

    // ---- phase 3: coeffs + row byte offsets ----
    for (int u = tid; u < 288; u += 256) {
        int kk = u >> 5, pos = u & 31;
        float offy = omr[2 * kk][pos] + b_off[2 * kk];
        float offx = omr[2 * kk + 1][pos] + b_off[2 * kk + 1];
        float mk = 1.0f / (1.0f + __expf(-(omr[18 + kk][pos] + b_msk[kk])));
        float py = offy + (float)(kk / 3) + (float)h2;
        float px = offx + (float)(kk % 3) + (float)(w0 + pos - 1);

        float y0f = floorf(py), x0f = floorf(px);
        float dy = py - y0f, dx = px - x0f;
        int y0 = (int)y0f, x0 = (int)x0f;
        int y1 = y0 + 1, x1 = x0 + 1;
        bool vy0 = (unsigned)y0 < (unsigned)HH;
        bool vy1 = (unsigned)y1 < (unsigned)HH;
        bool vx0 = (unsigned)x0 < (unsigned)WW;
        bool vx1 = (unsigned)x1 < (unsigned)WW;
        float w00 = (1.0f - dy) * (1.0f - dx) * ((vy0 && vx0) ? mk : 0.0f);
        float w01 = (1.0f - dy) * dx          * ((vy0 && vx1) ? mk : 0.0f);
        float w10 = dy * (1.0f - dx)          * ((vy1 && vx0) ? mk : 0.0f);
        float w11 = dy * dx                   * ((vy1 && vx1) ? mk : 0.0f);
        int xbase = min(max(x0, 0), WW - 2);
        bool s0 = x0 > xbase;
        bool s1 = x1 > xbase;
        float4 cf;
        cf.x = (s0 ? 0.f : w00) + (s1 ? 0.f : w01);
        cf.y = (s0 ? w00 : 0.f) + (s1 ? w01 : 0.f);
        cf.z = (s0 ? 0.f : w10) + (s1 ? 0.f : w11);
        cf.w = (s0 ? w10 : 0.f) + (s1 ? w11 : 0.f);
        int yc0 = min(max(y0, 0), HH - 1);
        int yc1 = min(max(y1, 0), HH - 1);
        metaC[u] = cf;
        uint2 mr;
        mr.x = (unsigned)(yc0 * WW + xbase) * 256u;   // byte offset in xP slab
        mr.y = (unsigned)(yc1 * WW + xbase) * 256u;
        metaR[u] = mr;
    }
    __syncthreads();

    // ---- phase 4: all-tap sampling (no barriers) ----
    int p0 = wv * 8;
    int c = lane;
    int c4 = 4 * c;
    const char* xPb = (const char*)(xP + (size_t)b * HW * 64);
    unsigned int G0[2][8], G1[2][8];

    auto issue = [&](int k, int sel) {
#pragma unroll
        for (int i = 0; i < 8; ++i) {
            uint2 mr = metaR[k * 32 + p0 + i];               // broadcast
            unsigned r0 = __builtin_amdgcn_readfirstlane(mr.x);
            unsigned r1 = __builtin_amdgcn_readfirstlane(mr.y);
            G0[sel][i] = *(const unsigned int*)(xPb + r0 + c4);  // SGPR base
            G1[sel][i] = *(const unsigned int*)(xPb + r1 + c4);
        }
    };
    auto store = [&](int k, int sel) {
#pragma unroll
        for (int i = 0; i < 8; ++i) {
            float4 cf = metaC[k * 32 + p0 + i];              // broadcast
            float v = cf.x * bflo(G0[sel][i]) + cf.y * bfhi(G0[sel][i])
                    + cf.z * bflo(G1[sel][i]) + cf.w * bfhi(G1[sel][i]);
            int pos = p0 + i;
            S[k][pos][((c >> 3) ^ (pos & 7)) * 8 + (c & 7)] = f2bf(v);
        }
    };

    issue(0, 0);
#pragma unroll
    for (int k = 0; k < 9; ++k) {
        if (k < 8) issue(k + 1, (k + 1) & 1);   // next tap's loads in flight
        store(k, k & 1);
    }
    __syncthreads();                   // the ONE sampling barrier

    // ---- MFMA burst: 36 back-to-back ----
    floatx4 acc0 = (floatx4){0.f, 0.f, 0.f, 0.f};
    floatx4 acc1 = (floatx4){0.f, 0.f, 0.f, 0.f};
#pragma unroll
    for (int k = 0; k < 9; ++k) {
        const unsigned short* wk = W2 + ((size_t)(k * OC) + wv * 16 + m16) * CC + q * 8;
#pragma unroll
        for (int s = 0; s < 2; ++s) {
            short8 af = *(const short8*)(wk + s * 32);
            int cb = ((q + 4 * s) ^ (m16 & 7)) * 8;
            short8 bf0 = *(const short8*)&S[k][m16][cb];
            short8 bf1 = *(const short8*)&S[k][16 + m16][cb];
            acc0 = __builtin_amdgcn_mfma_f32_16x16x32_bf16(af, bf0, acc0, 0, 0, 0);
            acc1 = __builtin_amdgcn_mfma_f32_16x16x32_bf16(af, bf1, acc1, 0, 0, 0);
        }
    }

    // epilogue: C/D col=lane&15 (pos), row=(lane>>4)*4+reg (o)
#pragma unroll
    for (int nt = 0; nt < 2; ++nt) {
        floatx4 av = nt ? acc1 : acc0;
#pragma unroll
        for (int r = 0; r < 4; ++r) {
            int o = wv * 16 + q * 4 + r;
            out[(((size_t)b * OC + o) * HO + h) * WO + w0 + nt * 16 + m16] = av[r];
        }
    }
}

// ---------------------------------------------------------------------------
extern "C" void kernel_launch(void* const* d_in, const int* in_sizes, int n_in,
                              void* d_out, int out_size, void* d_ws, size_t ws_size,
                              hipStream_t stream)
{
    const float* x      = (const float*)d_in[0];
    const float* w_off  = (const float*)d_in[1];
    const float* b_off  = (const float*)d_in[2];
    const float* w_msk  = (const float*)d_in[3];
    const float* b_msk  = (const float*)d_in[4];
    const float* w_conv = (const float*)d_in[5];
    float* out = (float*)d_out;

    unsigned short* xT = (unsigned short*)d_ws;                    // 16.8 MB
    unsigned int* xP = (unsigned int*)(xT + (size_t)BB * HW * 64); // 33.6 MB
    unsigned short* Wom = (unsigned short*)(xP + (size_t)BB * HW * 64);
    unsigned short* W2 = Wom + 32 * 576;

    prep<<<dim3(1132), dim3(512), 0, stream>>>(x, w_off, w_msk, w_conv,
                                               xT, xP, Wom, W2);
    fused<<<dim3(2048), dim3(256), 0, stream>>>(xT, xP, Wom, W2,
                                                b_off, b_msk, out);
}